// Round 10
// baseline (186.142 us; speedup 1.0000x reference)
//
#include <hip/hip_runtime.h>

#define LAMC    10000.0f
#define INV_LAM 1e-4f
#define EPSC    1e-12f
#define TOLC    1e-6f
#define BLK     256
#define NR      4            // rows per thread, fully interleaved

__device__ __forceinline__ float frcp(float x)  { return __builtin_amdgcn_rcpf(x); }
__device__ __forceinline__ float frsq(float x)  { return __builtin_amdgcn_rsqf(x); }
__device__ __forceinline__ float fsqrt_(float x){ return __builtin_amdgcn_sqrtf(x); }

// sign(phi(t)) without sqrt/div: phi = L - R*sqrt(q), q >= EPS > 0
__device__ __forceinline__ bool phi_pos(float t, float A, float p, float N, float b) {
    float q  = fmaxf(fmaf(t, fmaf(t, A, -2.0f * p), N), EPSC);
    float L  = fmaf(-t, A, p);        // p - t*A   (U_MAX = 1)
    float R  = fmaf(t, INV_LAM, b);   // b + t/LAM
    float L2 = L * L;
    float Rq = (R * R) * q;
    return (R < 0.0f) ? ((L >= 0.0f) || (L2 < Rq))
                      : ((L >  0.0f) && (L2 > Rq));
}

// easy paths; returns true if heavy (branch 3). Exports (ax,ay,b).
// Numerics identical to passing rounds 6/9.
__device__ __forceinline__ bool easy_row(float ux, float uy,
                                         float px, float py, float vx, float vy,
                                         float& ox, float& oy,
                                         float& axo, float& ayo, float& bo) {
    float ax = -2.0f * px, ay = -2.0f * py;
    float h  = fmaf(px, px, py * py) - 1.0f;
    float b  = fmaf(2.0f, h, -2.0f * fmaf(px, vx, py * vy));
    axo = ax; ayo = ay; bo = b;
    float A  = fmaf(ax, ax, ay * ay);
    float p  = fmaf(ax, ux, ay * uy);
    float N  = fmaf(ux, ux, uy * uy);
    float s1 = fminf(1.0f, frsq(fmaxf(N, EPSC)));   // min(1, 1/|u|)
    float u1x = ux * s1, u1y = uy * s1;
    ox = u1x; oy = u1y;
    if (fmaf(ax, u1x, ay * u1y) <= b + TOLC) return false;
    float t2  = LAMC * (p - b) * frcp(fmaf(LAMC, A, 1.0f));
    float u2x = fmaf(-t2, ax, ux), u2y = fmaf(-t2, ay, uy);
    if (t2 >= -TOLC && fmaf(u2x, u2x, u2y * u2y) <= 1.0f + TOLC) {
        ox = u2x; oy = u2y; return false;
    }
    return true;
}

// Branchless 4-way interleaved branch-3 solver. Per-row math identical to the
// passing R6/R9 solver: proven bracket, 12 bisections, 5 safeguarded Newton;
// collapse rows (phi(0)<=0) use a separate 3-step unclamped Newton from 0
// (replicating the reference exactly). Rows that are not heavy compute
// garbage that is discarded by the caller's select — no traps on GPU.
__device__ __forceinline__ void heavy4(const float ux[NR], const float uy[NR],
                                       const float ax[NR], const float ay[NR],
                                       const float bb[NR],
                                       float t3o[NR], float invk[NR]) {
    float A[NR], p[NR], N[NR], lo[NR], hi[NR], tb[NR];
    bool pos0[NR];
    #pragma unroll
    for (int r = 0; r < NR; ++r) {
        A[r] = fmaf(ax[r], ax[r], ay[r] * ay[r]);
        p[r] = fmaf(ax[r], ux[r], ay[r] * uy[r]);
        N[r] = fmaf(ux[r], ux[r], uy[r] * uy[r]);
        pos0[r] = phi_pos(0.0f, A[r], p[r], N[r], bb[r]);
        float tA = p[r] * frcp(fmaxf(A[r], 1e-30f));
        bool c1 = (p[r] > 0.0f) && (fmaf(tA, INV_LAM, bb[r]) >= 0.0f);
        bool c2 = (p[r] > 0.0f) && !c1;
        lo[r] = c2 ? tA : 0.0f;
        hi[r] = c1 ? tA : -LAMC * bb[r];
    }
    // 12 bisections, 4 rows interleaved
    #pragma unroll 1
    for (int k = 0; k < 12; ++k) {
        #pragma unroll
        for (int r = 0; r < NR; ++r) {
            float mid = 0.5f * (lo[r] + hi[r]);
            bool pos = phi_pos(mid, A[r], p[r], N[r], bb[r]);
            lo[r] = pos ? mid : lo[r];
            hi[r] = pos ? hi[r] : mid;
        }
    }
    #pragma unroll
    for (int r = 0; r < NR; ++r) tb[r] = 0.5f * (lo[r] + hi[r]);
    // 5 safeguarded Newton, interleaved
    #pragma unroll 1
    for (int k = 0; k < 5; ++k) {
        #pragma unroll
        for (int r = 0; r < NR; ++r) {
            float q   = fmaxf(fmaf(tb[r], fmaf(tb[r], A[r], -2.0f * p[r]), N[r]), EPSC);
            float nrm = fsqrt_(q);
            float R   = fmaf(tb[r], INV_LAM, bb[r]);
            float f   = fmaf(-tb[r], A[r], p[r]) - R * nrm;
            float df  = -A[r] - nrm * INV_LAM - R * fmaf(tb[r], A[r], -p[r]) * frcp(nrm);
            df = (fabsf(df) > 1e-8f) ? df : -1e-8f;
            bool fp = f > 0.0f;
            lo[r] = fp ? tb[r] : lo[r];
            hi[r] = fp ? hi[r] : tb[r];
            tb[r] = fminf(fmaxf(tb[r] - f * frcp(df), lo[r]), hi[r]);
        }
    }
    // collapse path: exactly 3 unclamped Newton from 0 (reference semantics)
    float tc[NR];
    #pragma unroll
    for (int r = 0; r < NR; ++r) tc[r] = 0.0f;
    #pragma unroll 1
    for (int k = 0; k < 3; ++k) {
        #pragma unroll
        for (int r = 0; r < NR; ++r) {
            float q   = fmaxf(fmaf(tc[r], fmaf(tc[r], A[r], -2.0f * p[r]), N[r]), EPSC);
            float nrm = fsqrt_(q);
            float R   = fmaf(tc[r], INV_LAM, bb[r]);
            float f   = fmaf(-tc[r], A[r], p[r]) - R * nrm;
            float df  = -A[r] - nrm * INV_LAM - R * fmaf(tc[r], A[r], -p[r]) * frcp(nrm);
            df = (fabsf(df) > 1e-8f) ? df : -1e-8f;
            tc[r] = tc[r] - f * frcp(df);
        }
    }
    #pragma unroll
    for (int r = 0; r < NR; ++r) {
        float t3  = pos0[r] ? tb[r] : tc[r];
        float q3  = fmaxf(fmaf(t3, fmaf(t3, A[r], -2.0f * p[r]), N[r]), EPSC);
        float k3  = fmaxf(fsqrt_(q3), 1.0f);
        t3o[r]  = t3;
        invk[r] = frcp(k3);
    }
}

// 2 pairs (4 rows) per thread, fully branchless heavy path with 4-way ILP.
__global__ __launch_bounds__(BLK) void cbf_kernel(const float4* __restrict__ u4,
                                                  const float4* __restrict__ obs4,
                                                  float4* __restrict__ out4,
                                                  int npair) {
    int tid = threadIdx.x;
    int pA  = blockIdx.x * (2 * BLK) + tid;   // pair 0 (coalesced)
    int pB  = pA + BLK;                       // pair 1 (coalesced)
    bool vA = pA < npair, vB = pB < npair;

    float4 z = make_float4(0.f, 0.f, 0.f, 0.f);
    float4 uA = z, a0 = z, a1 = z, a2 = z;
    float4 uB = z, b0 = z, b1 = z, b2 = z;
    if (vA) { uA = u4[pA]; a0 = obs4[3 * pA]; a1 = obs4[3 * pA + 1]; a2 = obs4[3 * pA + 2]; }
    if (vB) { uB = u4[pB]; b0 = obs4[3 * pB]; b1 = obs4[3 * pB + 1]; b2 = obs4[3 * pB + 2]; }

    // pair layout: row 2p:   p_rel=(o0.z,o0.w) v=(o1.x,o1.y)
    //              row 2p+1: p_rel=(o2.x,o2.y) v=(o2.z,o2.w)
    float ux[NR] = {uA.x, uA.z, uB.x, uB.z};
    float uy[NR] = {uA.y, uA.w, uB.y, uB.w};
    float ox[NR], oy[NR], ax[NR], ay[NR], bb[NR];
    bool  hv[NR];
    hv[0] = easy_row(ux[0], uy[0], a0.z, a0.w, a1.x, a1.y, ox[0], oy[0], ax[0], ay[0], bb[0]);
    hv[1] = easy_row(ux[1], uy[1], a2.x, a2.y, a2.z, a2.w, ox[1], oy[1], ax[1], ay[1], bb[1]);
    hv[2] = easy_row(ux[2], uy[2], b0.z, b0.w, b1.x, b1.y, ox[2], oy[2], ax[2], ay[2], bb[2]);
    hv[3] = easy_row(ux[3], uy[3], b2.x, b2.y, b2.z, b2.w, ox[3], oy[3], ax[3], ay[3], bb[3]);

    float t3[NR], ik[NR];
    heavy4(ux, uy, ax, ay, bb, t3, ik);

    #pragma unroll
    for (int r = 0; r < NR; ++r) {
        float hx = fmaf(-t3[r], ax[r], ux[r]) * ik[r];
        float hy = fmaf(-t3[r], ay[r], uy[r]) * ik[r];
        ox[r] = hv[r] ? hx : ox[r];
        oy[r] = hv[r] ? hy : oy[r];
    }
    if (vA) out4[pA] = make_float4(ox[0], oy[0], ox[1], oy[1]);
    if (vB) out4[pB] = make_float4(ox[2], oy[2], ox[3], oy[3]);
}

extern "C" void kernel_launch(void* const* d_in, const int* in_sizes, int n_in,
                              void* d_out, int out_size, void* d_ws, size_t ws_size,
                              hipStream_t stream) {
    const float* u_nom = (const float*)d_in[0];
    const float* obs   = (const float*)d_in[1];
    float* out = (float*)d_out;
    int rows   = in_sizes[0] / 2;                 // B
    int npair  = rows / 2;                        // float4 pairs
    int blocks = (npair + 2 * BLK - 1) / (2 * BLK);
    cbf_kernel<<<blocks, BLK, 0, stream>>>((const float4*)u_nom,
                                           (const float4*)obs,
                                           (float4*)out, npair);
}